// Round 4
// baseline (146.892 us; speedup 1.0000x reference)
//
#include <hip/hip_runtime.h>

#define BB    16384
#define NF    24
#define CARDN 10000
#define DD    16
#define NI    276       // 24*23/2  (> 256 threads! pairs handled 2 per thread)
#define H1N   128
#define H2N   64
#define SB    16        // samples per block
#define RSTR  392       // rows_s row stride (384 + 8 pad, floats)
#define PSTR  17        // pairsT sample stride (16 + 1 pad)
#define HSTR  17        // h1T/h2T sample stride

// ---------------------------------------------------------------------------
// Fully fused: per block of SB samples,
//   phase 1 (per sample): coalesced load of 24 rows E[i, x_i, :, :] (1536 B
//            contiguous each) into LDS -> 276 pair dot products -> pairsT
//   phase 2: f32 MLP 276->128->64->1 on the SB-sample tile + linear term.
// R4 fix: NI=276 > 256 threads — each thread now computes pairs p=tid and
// p=tid+256 (R3 left pairsT[256..275] uninitialized -> absmax 0.26).
// ---------------------------------------------------------------------------
__global__ __launch_bounds__(256) void fanfm_fused_kernel(
    const int* __restrict__ x, const float* __restrict__ E,
    const float* __restrict__ Wlin, const float* __restrict__ blin,
    const float* __restrict__ W1, const float* __restrict__ b1,
    const float* __restrict__ W2, const float* __restrict__ b2,
    const float* __restrict__ W3, const float* __restrict__ b3,
    float* __restrict__ out)
{
    __shared__ float rows_s[NF * RSTR];     // 37632 B (one sample's 24 rows)
    __shared__ float pairsT[NI * PSTR];     // 18768 B, [p][s]
    __shared__ int   xs[SB * NF];           // 1536 B
    __shared__ float lin_s[SB];             // 64 B

    float* h1T = rows_s;                    // [H1N][HSTR] overlays rows_s
    float* h2T = rows_s + H1N * HSTR;       // [H2N][HSTR]

    const int tid = threadIdx.x;
    const int b0  = blockIdx.x * SB;

    // --- stage x tile (384 entries, 256 threads -> strided loop) ---
    for (int idx = tid; idx < SB * NF; idx += 256) xs[idx] = x[b0 * NF + idx];
    __syncthreads();

    // --- linear term (+ blin + b3 folded); overlaps with gather loop ---
    if (tid < SB) {
        float l = blin[0] + b3[0];
        #pragma unroll
        for (int i = 0; i < NF; ++i) l += Wlin[i * CARDN + xs[tid * NF + i]];
        lin_s[tid] = l;
    }

    // --- pair index decode, hoisted, for p = tid and p = tid + 256 ---
    int pi0, pj0, pi1 = -1, pj1 = -1;
    {
        int i = 0, rem = tid, cnt = NF - 1;
        while (rem >= cnt) { rem -= cnt; --cnt; ++i; }
        pi0 = i; pj0 = i + 1 + rem;
    }
    if (tid + 256 < NI) {
        int i = 0, rem = tid + 256, cnt = NF - 1;
        while (rem >= cnt) { rem -= cnt; --cnt; ++i; }
        pi1 = i; pj1 = i + 1 + rem;
    }

    // --- phase 1: per-sample gather + pair dots ---
    for (int s = 0; s < SB; ++s) {
        __syncthreads();   // prev sample's pair reads of rows_s are done
        // load 24 rows (each 96 float4, contiguous) -> 2304 float4 / 256 thr
        #pragma unroll
        for (int k = 0; k < 9; ++k) {
            int idx = tid + k * 256;              // < NF*96 = 2304
            int r   = idx / 96;
            int cq  = idx - r * 96;
            const float4 v = *(const float4*)(E +
                ((size_t)r * CARDN + xs[s * NF + r]) * (NF * DD) + cq * 4);
            *(float4*)(rows_s + r * RSTR + cq * 4) = v;
        }
        __syncthreads();   // rows ready
        {
            const float4* a = (const float4*)(rows_s + pi0 * RSTR + pj0 * DD);
            const float4* c = (const float4*)(rows_s + pj0 * RSTR + pi0 * DD);
            float4 a0 = a[0], a1 = a[1], a2 = a[2], a3 = a[3];
            float4 c0 = c[0], c1 = c[1], c2 = c[2], c3 = c[3];
            float d =
                a0.x*c0.x + a0.y*c0.y + a0.z*c0.z + a0.w*c0.w +
                a1.x*c1.x + a1.y*c1.y + a1.z*c1.z + a1.w*c1.w +
                a2.x*c2.x + a2.y*c2.y + a2.z*c2.z + a2.w*c2.w +
                a3.x*c3.x + a3.y*c3.y + a3.z*c3.z + a3.w*c3.w;
            pairsT[tid * PSTR + s] = d;
        }
        if (pi1 >= 0) {
            const float4* a = (const float4*)(rows_s + pi1 * RSTR + pj1 * DD);
            const float4* c = (const float4*)(rows_s + pj1 * RSTR + pi1 * DD);
            float4 a0 = a[0], a1 = a[1], a2 = a[2], a3 = a[3];
            float4 c0 = c[0], c1 = c[1], c2 = c[2], c3 = c[3];
            float d =
                a0.x*c0.x + a0.y*c0.y + a0.z*c0.z + a0.w*c0.w +
                a1.x*c1.x + a1.y*c1.y + a1.z*c1.z + a1.w*c1.w +
                a2.x*c2.x + a2.y*c2.y + a2.z*c2.z + a2.w*c2.w +
                a3.x*c3.x + a3.y*c3.y + a3.z*c3.z + a3.w*c3.w;
            pairsT[(tid + 256) * PSTR + s] = d;
        }
    }
    __syncthreads();       // pairsT complete; rows_s free for h1T/h2T

    // --- GEMM1: h1[s][c] = relu(sum_p pairs[s][p] * W1[p][c] + b1[c]) ---
    {
        const int c4 = tid & 31;   // cols c4*4 .. c4*4+3
        const int sg = tid >> 5;   // samples sg*2, sg*2+1
        float acc[2][4] = {};
        #pragma unroll 4
        for (int p = 0; p < NI; ++p) {
            float4 w = *(const float4*)(W1 + p * H1N + c4 * 4);
            float pr0 = pairsT[p * PSTR + sg * 2 + 0];
            float pr1 = pairsT[p * PSTR + sg * 2 + 1];
            acc[0][0] = fmaf(pr0, w.x, acc[0][0]);
            acc[0][1] = fmaf(pr0, w.y, acc[0][1]);
            acc[0][2] = fmaf(pr0, w.z, acc[0][2]);
            acc[0][3] = fmaf(pr0, w.w, acc[0][3]);
            acc[1][0] = fmaf(pr1, w.x, acc[1][0]);
            acc[1][1] = fmaf(pr1, w.y, acc[1][1]);
            acc[1][2] = fmaf(pr1, w.z, acc[1][2]);
            acc[1][3] = fmaf(pr1, w.w, acc[1][3]);
        }
        float4 bb = *(const float4*)(b1 + c4 * 4);
        #pragma unroll
        for (int si = 0; si < 2; ++si) {
            int s = sg * 2 + si;
            h1T[(c4 * 4 + 0) * HSTR + s] = fmaxf(acc[si][0] + bb.x, 0.f);
            h1T[(c4 * 4 + 1) * HSTR + s] = fmaxf(acc[si][1] + bb.y, 0.f);
            h1T[(c4 * 4 + 2) * HSTR + s] = fmaxf(acc[si][2] + bb.z, 0.f);
            h1T[(c4 * 4 + 3) * HSTR + s] = fmaxf(acc[si][3] + bb.w, 0.f);
        }
    }
    __syncthreads();

    // --- GEMM2: h2[s][c] = relu(sum_p h1[s][p] * W2[p][c] + b2[c]) ---
    {
        const int c16 = tid & 15;  // cols c16*4 .. +3
        const int sg2 = tid >> 4;  // sample (0..15)
        float acc[4] = {};
        #pragma unroll 4
        for (int p = 0; p < H1N; ++p) {
            float4 w = *(const float4*)(W2 + p * H2N + c16 * 4);
            float pr = h1T[p * HSTR + sg2];
            acc[0] = fmaf(pr, w.x, acc[0]);
            acc[1] = fmaf(pr, w.y, acc[1]);
            acc[2] = fmaf(pr, w.z, acc[2]);
            acc[3] = fmaf(pr, w.w, acc[3]);
        }
        float4 bb = *(const float4*)(b2 + c16 * 4);
        h2T[(c16 * 4 + 0) * HSTR + sg2] = fmaxf(acc[0] + bb.x, 0.f);
        h2T[(c16 * 4 + 1) * HSTR + sg2] = fmaxf(acc[1] + bb.y, 0.f);
        h2T[(c16 * 4 + 2) * HSTR + sg2] = fmaxf(acc[2] + bb.z, 0.f);
        h2T[(c16 * 4 + 3) * HSTR + sg2] = fmaxf(acc[3] + bb.w, 0.f);
    }
    __syncthreads();

    // --- GEMM3 + linear: out[s] = h2[s][:] . W3 + lin_s[s] ---
    {
        const int s  = tid >> 4;   // 0..15
        const int ko = tid & 15;   // 4 k's each
        float r = 0.f;
        #pragma unroll
        for (int kk = 0; kk < 4; ++kk) {
            int k = ko * 4 + kk;
            r = fmaf(h2T[k * HSTR + s], W3[k], r);
        }
        r += __shfl_xor(r, 1);
        r += __shfl_xor(r, 2);
        r += __shfl_xor(r, 4);
        r += __shfl_xor(r, 8);
        if (ko == 0) out[b0 + s] = r + lin_s[s];
    }
}

extern "C" void kernel_launch(void* const* d_in, const int* in_sizes, int n_in,
                              void* d_out, int out_size, void* d_ws, size_t ws_size,
                              hipStream_t stream) {
    const int*   x    = (const int*)  d_in[0];
    const float* E    = (const float*)d_in[1];
    const float* Wlin = (const float*)d_in[2];
    const float* blin = (const float*)d_in[3];
    const float* W1   = (const float*)d_in[4];
    const float* b1   = (const float*)d_in[5];
    const float* W2   = (const float*)d_in[6];
    const float* b2   = (const float*)d_in[7];
    const float* W3   = (const float*)d_in[8];
    const float* b3   = (const float*)d_in[9];
    float* out = (float*)d_out;

    fanfm_fused_kernel<<<BB / SB, 256, 0, stream>>>(
        x, E, Wlin, blin, W1, b1, W2, b2, W3, b3, out);
}

// Round 5
// 133.513 us; speedup vs baseline: 1.1002x; 1.1002x over previous
//
#include <hip/hip_runtime.h>

#define BB    16384
#define NF    24
#define CARDN 10000
#define DD    16
#define NI    276       // 24*23/2
#define H1N   128
#define H2N   64
#define SB    16        // samples per block
#define PSTR  17        // pairsT sample stride (16+1) -> stride-17 words, conflict-free
#define HSTR  17        // h1T/h2T sample stride

// ---------------------------------------------------------------------------
// Fused, latency-tolerant version (R5):
//  phase 1: BARRIER-FREE gather — each thread computes ~17 independent
//           (sample, pair) dot products with direct global float4 reads
//           (2 x 64 B per pair), writing into transposed LDS pairsT[p][s].
//           No staging LDS, no per-sample barriers (R4's mistake: 2 barriers
//           per sample + 2 blocks/CU could not hide HBM latency).
//  phase 2: f32 MLP 276->128->64->1 on the SB-sample tile + linear term.
//  ~31 KB LDS -> 4 blocks/CU; MLP-phase blocks overlap gather-phase blocks.
// ---------------------------------------------------------------------------
__global__ __launch_bounds__(256, 4) void fanfm_fused_kernel(
    const int* __restrict__ x, const float* __restrict__ E,
    const float* __restrict__ Wlin, const float* __restrict__ blin,
    const float* __restrict__ W1, const float* __restrict__ b1,
    const float* __restrict__ W2, const float* __restrict__ b2,
    const float* __restrict__ W3, const float* __restrict__ b3,
    float* __restrict__ out)
{
    __shared__ float pairsT[NI * PSTR];   // 18768 B, [p][s]
    __shared__ float h1T[H1N * HSTR];     //  8704 B, [c][s]
    __shared__ int   xs[SB * NF];         //  1536 B
    __shared__ float lin_s[SB];           //    64 B
    __shared__ int   pi_tab[NI];          //  1104 B
    __shared__ int   pj_tab[NI];          //  1104 B

    float* h2T = pairsT;                  // [H2N][HSTR] overlays pairsT after GEMM1

    const int tid = threadIdx.x;
    const int b0  = blockIdx.x * SB;

    // --- stage x tile + build pair-decode tables (one barrier) ---
    for (int idx = tid; idx < SB * NF; idx += 256) xs[idx] = x[b0 * NF + idx];
    for (int idx = tid; idx < NI; idx += 256) {
        int i = 0, rem = idx, cnt = NF - 1;
        while (rem >= cnt) { rem -= cnt; --cnt; ++i; }
        pi_tab[idx] = i;
        pj_tab[idx] = i + 1 + rem;
    }
    __syncthreads();

    // --- linear term (+ blin + b3 folded); overlaps with gather ---
    if (tid < SB) {
        float l = blin[0] + b3[0];
        #pragma unroll
        for (int i = 0; i < NF; ++i) l += Wlin[i * CARDN + xs[tid * NF + i]];
        lin_s[tid] = l;
    }

    // --- phase 1: barrier-free (sample,pair) dots, ~17 per thread ---
    #pragma unroll 2
    for (int k = 0; k < (SB * NI + 255) / 256; ++k) {
        int idx = tid + k * 256;
        if (idx < SB * NI) {
            int s = idx / NI;
            int p = idx - s * NI;
            int i = pi_tab[p];
            int j = pj_tab[p];
            int xi = xs[s * NF + i];
            int xj = xs[s * NF + j];
            const float4* a = (const float4*)(E + ((size_t)i * CARDN + xi) * (NF * DD) + j * DD);
            const float4* c = (const float4*)(E + ((size_t)j * CARDN + xj) * (NF * DD) + i * DD);
            float4 a0 = a[0], a1 = a[1], a2 = a[2], a3 = a[3];
            float4 c0 = c[0], c1 = c[1], c2 = c[2], c3 = c[3];
            float d =
                a0.x*c0.x + a0.y*c0.y + a0.z*c0.z + a0.w*c0.w +
                a1.x*c1.x + a1.y*c1.y + a1.z*c1.z + a1.w*c1.w +
                a2.x*c2.x + a2.y*c2.y + a2.z*c2.z + a2.w*c2.w +
                a3.x*c3.x + a3.y*c3.y + a3.z*c3.z + a3.w*c3.w;
            pairsT[p * PSTR + s] = d;   // stride-17 words: conflict-free
        }
    }
    __syncthreads();

    // --- GEMM1: h1[s][c] = relu(sum_p pairs[s][p] * W1[p][c] + b1[c]) ---
    {
        const int c4 = tid & 31;   // cols c4*4 .. c4*4+3
        const int sg = tid >> 5;   // samples sg*2, sg*2+1
        float acc[2][4] = {};
        #pragma unroll 4
        for (int p = 0; p < NI; ++p) {
            float4 w = *(const float4*)(W1 + p * H1N + c4 * 4);
            float pr0 = pairsT[p * PSTR + sg * 2 + 0];
            float pr1 = pairsT[p * PSTR + sg * 2 + 1];
            acc[0][0] = fmaf(pr0, w.x, acc[0][0]);
            acc[0][1] = fmaf(pr0, w.y, acc[0][1]);
            acc[0][2] = fmaf(pr0, w.z, acc[0][2]);
            acc[0][3] = fmaf(pr0, w.w, acc[0][3]);
            acc[1][0] = fmaf(pr1, w.x, acc[1][0]);
            acc[1][1] = fmaf(pr1, w.y, acc[1][1]);
            acc[1][2] = fmaf(pr1, w.z, acc[1][2]);
            acc[1][3] = fmaf(pr1, w.w, acc[1][3]);
        }
        float4 bb = *(const float4*)(b1 + c4 * 4);
        #pragma unroll
        for (int si = 0; si < 2; ++si) {
            int s = sg * 2 + si;
            h1T[(c4 * 4 + 0) * HSTR + s] = fmaxf(acc[si][0] + bb.x, 0.f);
            h1T[(c4 * 4 + 1) * HSTR + s] = fmaxf(acc[si][1] + bb.y, 0.f);
            h1T[(c4 * 4 + 2) * HSTR + s] = fmaxf(acc[si][2] + bb.z, 0.f);
            h1T[(c4 * 4 + 3) * HSTR + s] = fmaxf(acc[si][3] + bb.w, 0.f);
        }
    }
    __syncthreads();   // h1T ready; pairsT dead -> h2T overlays it

    // --- GEMM2: h2[s][c] = relu(sum_p h1[s][p] * W2[p][c] + b2[c]) ---
    {
        const int c16 = tid & 15;  // cols c16*4 .. +3
        const int sg2 = tid >> 4;  // sample (0..15)
        float acc[4] = {};
        #pragma unroll 4
        for (int p = 0; p < H1N; ++p) {
            float4 w = *(const float4*)(W2 + p * H2N + c16 * 4);
            float pr = h1T[p * HSTR + sg2];
            acc[0] = fmaf(pr, w.x, acc[0]);
            acc[1] = fmaf(pr, w.y, acc[1]);
            acc[2] = fmaf(pr, w.z, acc[2]);
            acc[3] = fmaf(pr, w.w, acc[3]);
        }
        float4 bb = *(const float4*)(b2 + c16 * 4);
        h2T[(c16 * 4 + 0) * HSTR + sg2] = fmaxf(acc[0] + bb.x, 0.f);
        h2T[(c16 * 4 + 1) * HSTR + sg2] = fmaxf(acc[1] + bb.y, 0.f);
        h2T[(c16 * 4 + 2) * HSTR + sg2] = fmaxf(acc[2] + bb.z, 0.f);
        h2T[(c16 * 4 + 3) * HSTR + sg2] = fmaxf(acc[3] + bb.w, 0.f);
    }
    __syncthreads();

    // --- GEMM3 + linear: out[s] = h2[s][:] . W3 + lin_s[s] ---
    {
        const int s  = tid >> 4;   // 0..15
        const int ko = tid & 15;   // 4 k's each
        float r = 0.f;
        #pragma unroll
        for (int kk = 0; kk < 4; ++kk) {
            int k = ko * 4 + kk;
            r = fmaf(h2T[k * HSTR + s], W3[k], r);
        }
        r += __shfl_xor(r, 1);
        r += __shfl_xor(r, 2);
        r += __shfl_xor(r, 4);
        r += __shfl_xor(r, 8);
        if (ko == 0) out[b0 + s] = r + lin_s[s];
    }
}

extern "C" void kernel_launch(void* const* d_in, const int* in_sizes, int n_in,
                              void* d_out, int out_size, void* d_ws, size_t ws_size,
                              hipStream_t stream) {
    const int*   x    = (const int*)  d_in[0];
    const float* E    = (const float*)d_in[1];
    const float* Wlin = (const float*)d_in[2];
    const float* blin = (const float*)d_in[3];
    const float* W1   = (const float*)d_in[4];
    const float* b1   = (const float*)d_in[5];
    const float* W2   = (const float*)d_in[6];
    const float* b2   = (const float*)d_in[7];
    const float* W3   = (const float*)d_in[8];
    const float* b3   = (const float*)d_in[9];
    float* out = (float*)d_out;

    fanfm_fused_kernel<<<BB / SB, 256, 0, stream>>>(
        x, E, Wlin, blin, W1, b1, W2, b2, W3, b3, out);
}